// Round 10
// baseline (333.384 us; speedup 1.0000x reference)
//
#include <hip/hip_runtime.h>
#include <cstdint>

#define BN 4
#define CIN 256
#define HALFC 128
#define HW 4096
#define SPLIT 8
#define JT 64
#define JITERS (HW / SPLIT / JT)   // 8

typedef float  floatx4 __attribute__((ext_vector_type(4)));
typedef short  shortx8 __attribute__((ext_vector_type(8)));

#if __has_builtin(__builtin_amdgcn_exp2f)
#define EXP2F(x) __builtin_amdgcn_exp2f(x)
#else
#define EXP2F(x) exp2f(x)
#endif
#define L2E 1.44269504088896f

__device__ __forceinline__ unsigned short f2bf(float f) {
  unsigned u = __float_as_uint(f);
  u += 0x7FFFu + ((u >> 16) & 1u);   // round-to-nearest-even
  return (unsigned short)(u >> 16);
}

__device__ __forceinline__ void async16(const void* g, void* l) {
  __builtin_amdgcn_global_load_lds((const __attribute__((address_space(1))) void*)g,
                                   (__attribute__((address_space(3))) void*)l, 16, 0, 0);
}

// ---------------- K0: cast/transpose x -> Xt [b][px][ci] bf16; W -> Wh bf16 -----------
__global__ __launch_bounds__(256) void k_split(const float* __restrict__ x,
    const float* __restrict__ w1, const float* __restrict__ w2,
    const float* __restrict__ w3, unsigned short* __restrict__ Xth,
    unsigned short* __restrict__ Wh) {
  __shared__ float smf[64 * 65];
  int bid = blockIdx.x;
  int t = threadIdx.x;
  if (bid < 1024) {
    int b = bid >> 8, rem = bid & 255;
    int cit = rem >> 6, pxt = rem & 63;     // ci tile (4), px tile (64)
    const float* src = x + (size_t)b * 1048576 + (size_t)(cit * 64) * HW + pxt * 64;
#pragma unroll
    for (int k = 0; k < 16; k++) {
      int idx = k * 256 + t;
      int r = idx >> 6, c = idx & 63;
      smf[r * 65 + c] = src[(size_t)r * HW + c];
    }
    __syncthreads();
    int prow = t >> 2, seg = t & 3;
    union { unsigned short us[16]; uint4 v[2]; } oh;
#pragma unroll
    for (int u = 0; u < 16; u++)
      oh.us[u] = f2bf(smf[(seg * 16 + u) * 65 + prow]);
    size_t dst = (size_t)b * 1048576 + (size_t)(pxt * 64 + prow) * 256 + cit * 64 + seg * 16;
    *(uint4*)(Xth + dst) = oh.v[0];
    *(uint4*)(Xth + dst + 8) = oh.v[1];
  } else {
    int bw = bid - 1024;                    // 0..11, each block 8192 elems
    int f0 = bw * 8192 + t * 32;
    const float* wsrc;
    int fo;
    if (f0 < 32768)      { wsrc = w1; fo = f0; }
    else if (f0 < 65536) { wsrc = w2; fo = f0 - 32768; }
    else                 { wsrc = w3; fo = f0 - 65536; }
    union { unsigned short us[32]; uint4 v[4]; } oh;
#pragma unroll
    for (int u = 0; u < 32; u++) oh.us[u] = f2bf(wsrc[fo + u]);
#pragma unroll
    for (int k = 0; k < 4; k++) *((uint4*)(Wh + f0) + k) = oh.v[k];
  }
}

// ---------------- K1: MFMA projection (bf16, fp32 acc), dbuf vmcnt pipeline ------------
// Round r stages [128 px][64 ci] fragment-order (16 KB); 16 MFMAs per barrier pair.
__global__ __launch_bounds__(256) void k_projM(const unsigned short* __restrict__ Xth,
    const unsigned short* __restrict__ Wh, unsigned short* __restrict__ Q,
    unsigned short* __restrict__ Kt, unsigned short* __restrict__ n3) {
  __shared__ unsigned short XhS[2 * 8192];  // 2 x 16 KB
  __shared__ unsigned short ES[9216];       // epilogue stage (18 KB)
  int bid = blockIdx.x;
  int pxt = bid & 31;
  int ct = bid >> 5;                        // b*6 + cot
  int b = ct / 6, cot = ct % 6;
  int px0 = pxt * 128, co0 = cot * 64;
  int t = threadIdx.x;
  int w = t >> 6, lane = t & 63, l16 = lane & 15, quad = lane >> 4;

  int myco = co0 + w * 16 + l16;
  shortx8 whf[8];
#pragma unroll
  for (int s = 0; s < 8; s++)
    whf[s] = *(const shortx8*)(Wh + (size_t)myco * 256 + s * 32 + quad * 8);
  __asm__ __volatile__("s_waitcnt vmcnt(0)" ::: "memory");  // drain whf: vmcnt exactness

  floatx4 acc[8];
  floatx4 zf = {0.f, 0.f, 0.f, 0.f};
#pragma unroll
  for (int mt = 0; mt < 8; mt++) acc[mt] = zf;
  const unsigned short* XhB = Xth + (size_t)b * 1048576;

  // staging source for (round r, chunk c4): slot mt=(c4*4+w)>>1, sk=(c4*4+w)&1
  // g = (px0 + mt*16 + l16)*256 + r*64 + sk*32 + quad*8
#define PROJ_SRC(r, c4) (XhB + (size_t)(px0 + (((c4) * 4 + w) >> 1) * 16 + l16) * 256 \
                         + (r) * 64 + (((c4) * 4 + w) & 1) * 32 + quad * 8)
  // prologue: round 0 -> buf 0
#pragma unroll
  for (int c4 = 0; c4 < 4; c4++)
    async16(PROJ_SRC(0, c4), (char*)XhS + c4 * 4096 + w * 1024);

#pragma unroll
  for (int r = 0; r < 4; r++) {
    int cur = r & 1, nxt = cur ^ 1;
    __asm__ __volatile__("s_barrier" ::: "memory");          // compute(r-1) done
    if (r + 1 < 4) {
#pragma unroll
      for (int c4 = 0; c4 < 4; c4++)
        async16(PROJ_SRC(r + 1, c4), (char*)XhS + nxt * 16384 + c4 * 4096 + w * 1024);
      __asm__ __volatile__("s_waitcnt vmcnt(4)" ::: "memory");
    } else {
      __asm__ __volatile__("s_waitcnt vmcnt(0)" ::: "memory");
    }
    __asm__ __volatile__("s_barrier" ::: "memory");          // round-r data landed
    const char* xb = (const char*)XhS + cur * 16384;
#pragma unroll
    for (int sk = 0; sk < 2; sk++)
#pragma unroll
      for (int mt = 0; mt < 8; mt++) {
        shortx8 ah = *(const shortx8*)(xb + (mt * 2 + sk) * 1024 + lane * 16);
        acc[mt] = __builtin_amdgcn_mfma_f32_16x16x32_bf16(ah, whf[r * 2 + sk], acc[mt], 0, 0, 0);
      }
  }
#undef PROJ_SRC
  __syncthreads();
  // D layout: element [px = mt*16 + quad*4 + rr][co_l = w*16 + l16]
  if (cot < 2 || cot >= 4) {             // Q / n3: stage [co][px]
    int co_l = w * 16 + l16;
#pragma unroll
    for (int mt = 0; mt < 8; mt++) {
      int px = mt * 16 + quad * 4;
      unsigned lo = (unsigned)f2bf(acc[mt][0]) | ((unsigned)f2bf(acc[mt][1]) << 16);
      unsigned hi = (unsigned)f2bf(acc[mt][2]) | ((unsigned)f2bf(acc[mt][3]) << 16);
      *(uint2*)(ES + co_l * 136 + px) = make_uint2(lo, hi);
    }
    __syncthreads();
    int cr = t >> 2, seg = t & 3;
    unsigned short* dstb = (cot < 2)
        ? Q  + (size_t)b * 524288 + (size_t)(co0 + cr) * HW
        : n3 + (size_t)b * 524288 + (size_t)(co0 - 256 + cr) * HW;
#pragma unroll
    for (int k2 = 0; k2 < 4; k2++) {
      uint4 v = *(const uint4*)(ES + cr * 136 + seg * 32 + k2 * 8);
      *(uint4*)(dstb + px0 + seg * 32 + k2 * 8) = v;
    }
  } else {                               // Kt: stage [px][co]
#pragma unroll
    for (int mt = 0; mt < 8; mt++)
#pragma unroll
      for (int rr = 0; rr < 4; rr++) {
        int px = mt * 16 + quad * 4 + rr;
        ES[px * 72 + w * 16 + l16] = f2bf(acc[mt][rr]);
      }
    __syncthreads();
    int ch0 = co0 - 128;
#pragma unroll
    for (int it = 0; it < 4; it++) {
      int cid = it * 256 + t;
      int px = cid >> 3, c8 = cid & 7;
      uint4 v = *(const uint4*)(ES + px * 72 + c8 * 8);
      *(uint4*)(Kt + (size_t)b * 524288 + (size_t)(px0 + px) * 128 + ch0 + c8 * 8) = v;
    }
  }
}

// ---------------- K2: VtF: V in wave-fragment order for direct coalesced PV loads ------
__global__ __launch_bounds__(256) void k_layoutVF(const unsigned short* __restrict__ n3,
    unsigned short* __restrict__ VtF) {
  __shared__ unsigned short sm[8192];
  int bid = blockIdx.x;                  // 256 = b(4) x jt(64)
  int b = bid >> 6, jt = bid & 63;
  int t = threadIdx.x;
  const unsigned short* src = n3 + (size_t)b * 524288 + (size_t)(jt * 2) * 4096;
#pragma unroll
  for (int k = 0; k < 32; k++) sm[k * 256 + t] = src[k * 256 + t];
  __syncthreads();
  unsigned short* dst = VtF + (size_t)b * 524288 + (size_t)jt * 8192;
#pragma unroll
  for (int k = 0; k < 4; k++) {
    int s = k * 256 + t;
    int nt = s >> 7, kt = (s >> 6) & 1, quad = (s >> 4) & 3, l16 = s & 15;
    union { unsigned short us[8]; uint4 v; } o;
#pragma unroll
    for (int e = 0; e < 8; e++)
      o.us[e] = sm[kt * 4096 + (quad * 8 + e) * 128 + nt * 16 + l16];
    *(uint4*)(dst + s * 8) = o.v;
  }
}

// ---------------- K3: fused flash attention (SPLIT=8 for 3 blocks/CU) -------------------
__global__ __launch_bounds__(256, 3) void k_flash(const unsigned short* __restrict__ Q,
    const unsigned short* __restrict__ Kt, const unsigned short* __restrict__ VtF,
    float* __restrict__ Opart, float* __restrict__ ml) {
  __shared__ unsigned short KtS[2 * 8192];   // 2 x 16 KB
  __shared__ unsigned short PS[4 * 32 * 64]; // 16 KB (4 KB per wave)
  int bid = blockIdx.x;
  int itile = bid & 31, sp = (bid >> 5) & 7, b = bid >> 8;
  int t = threadIdx.x;
  int w = t >> 6, lane = t & 63, l16 = lane & 15, quad = lane >> 4;
  int i0 = itile * 128;

  shortx8 qf[2][4];
#pragma unroll
  for (int ig = 0; ig < 2; ig++) {
    const unsigned short* qp = Q + ((size_t)b * HW + i0 + w * 32 + ig * 16 + l16) * 128 + quad * 8;
#pragma unroll
    for (int ks = 0; ks < 4; ks++) qf[ig][ks] = *(const shortx8*)(qp + ks * 32);
  }
  __asm__ __volatile__("s_waitcnt vmcnt(0)" ::: "memory");  // drain Q loads

  floatx4 O[2][8];
  floatx4 zf = {0.f, 0.f, 0.f, 0.f};
#pragma unroll
  for (int ig = 0; ig < 2; ig++)
#pragma unroll
    for (int nt = 0; nt < 8; nt++) O[ig][nt] = zf;
  float m_i[2] = {-1e30f, -1e30f}, l_i[2] = {0.f, 0.f};

  int ccK = w * 4 + (lane >> 4);
  const unsigned short* kbase = Kt + (size_t)b * HW * 128
                              + (size_t)(sp * 512 + l16) * 128 + ccK * 8;
  const unsigned short* vB = VtF + (size_t)b * 524288 + (size_t)(sp * 8) * 8192 + lane * 8;
  char* Pw = (char*)PS + w * 4096;

  // prologue: stage Kt tile 0 into buffer 0 (4 async16, left in flight)
#pragma unroll
  for (int c4 = 0; c4 < 4; c4++)
    async16(kbase + c4 * 2048, (char*)KtS + c4 * 4096 + w * 1024);

  for (int it = 0; it < JITERS; it++) {
    int cur = it & 1, nxt = cur ^ 1;
    __asm__ __volatile__("s_barrier" ::: "memory");   // compute(it-1) done
    // vf loads for tile it (global, coalesced) — issued BEFORE prefetch (vmcnt order)
    shortx8 vf[8][2];
    {
      const unsigned short* vt = vB + (size_t)it * 8192;
#pragma unroll
      for (int nt = 0; nt < 8; nt++)
#pragma unroll
        for (int kt = 0; kt < 2; kt++)
          vf[nt][kt] = *(const shortx8*)(vt + (nt * 2 + kt) * 512);
    }
    if (it + 1 < JITERS) {
      const unsigned short* kp = kbase + (size_t)(it + 1) * 8192;
#pragma unroll
      for (int c4 = 0; c4 < 4; c4++)
        async16(kp + c4 * 2048, (char*)KtS + nxt * 16384 + c4 * 4096 + w * 1024);
      __asm__ __volatile__("s_waitcnt vmcnt(20)" ::: "memory");
    } else {
      __asm__ __volatile__("s_waitcnt vmcnt(16)" ::: "memory");
    }
    __asm__ __volatile__("s_barrier" ::: "memory");   // tile-it Kt landed

    const char* kc = (const char*)KtS + cur * 16384;

    // ---- QK ----
    floatx4 S[2][4];
#pragma unroll
    for (int ig = 0; ig < 2; ig++)
#pragma unroll
      for (int mt = 0; mt < 4; mt++) S[ig][mt] = zf;
#pragma unroll
    for (int mt = 0; mt < 4; mt++) {
#pragma unroll
      for (int ks = 0; ks < 4; ks++) {
        shortx8 af = *(const shortx8*)(kc + mt * 4096 + ks * 1024 + lane * 16);
        S[0][mt] = __builtin_amdgcn_mfma_f32_16x16x32_bf16(af, qf[0][ks], S[0][mt], 0, 0, 0);
        S[1][mt] = __builtin_amdgcn_mfma_f32_16x16x32_bf16(af, qf[1][ks], S[1][mt], 0, 0, 0);
      }
    }
    // ---- online softmax per i-group; P overwrites S ----
    float alpha[2];
#pragma unroll
    for (int ig = 0; ig < 2; ig++) {
      float tmax = S[ig][0][0];
#pragma unroll
      for (int mt = 0; mt < 4; mt++)
#pragma unroll
        for (int rr = 0; rr < 4; rr++) tmax = fmaxf(tmax, S[ig][mt][rr]);
      tmax = fmaxf(tmax, __shfl_xor(tmax, 16));
      tmax = fmaxf(tmax, __shfl_xor(tmax, 32));
      float mnew = fmaxf(m_i[ig], tmax);
      alpha[ig] = EXP2F((m_i[ig] - mnew) * L2E);
      float tsum = 0.f;
#pragma unroll
      for (int mt = 0; mt < 4; mt++)
#pragma unroll
        for (int rr = 0; rr < 4; rr++) {
          float p = EXP2F((S[ig][mt][rr] - mnew) * L2E);
          S[ig][mt][rr] = p;
          tsum += p;
        }
      tsum += __shfl_xor(tsum, 16);
      tsum += __shfl_xor(tsum, 32);
      l_i[ig] = l_i[ig] * alpha[ig] + tsum;
      m_i[ig] = mnew;
    }
    if (__ballot(alpha[0] < 1.f || alpha[1] < 1.f)) {
#pragma unroll
      for (int ig = 0; ig < 2; ig++) {
        float ar[4];
#pragma unroll
        for (int rr = 0; rr < 4; rr++) ar[rr] = __shfl(alpha[ig], quad * 4 + rr);
#pragma unroll
        for (int nt = 0; nt < 8; nt++)
#pragma unroll
          for (int rr = 0; rr < 4; rr++) O[ig][nt][rr] *= ar[rr];
      }
    }
    // ---- P -> wave-private LDS; truncating bf16 pack via v_perm ----
#pragma unroll
    for (int ig = 0; ig < 2; ig++)
#pragma unroll
      for (int mt = 0; mt < 4; mt++) {
        unsigned lo = __builtin_amdgcn_perm(__float_as_uint(S[ig][mt][1]),
                                            __float_as_uint(S[ig][mt][0]), 0x07060302u);
        unsigned hi = __builtin_amdgcn_perm(__float_as_uint(S[ig][mt][3]),
                                            __float_as_uint(S[ig][mt][2]), 0x07060302u);
        *(uint2*)(Pw + ig * 2048 + (mt * 2 + (quad >> 1)) * 256 + l16 * 16 + (quad & 1) * 8)
            = make_uint2(lo, hi);
      }
    __asm__ __volatile__("s_waitcnt lgkmcnt(0)" ::: "memory");  // PS write->read
    if (it + 1 < JITERS) {
      __asm__ __volatile__("s_waitcnt vmcnt(4)" ::: "memory");  // vf landed, prefetch in flight
    } else {
      __asm__ __volatile__("s_waitcnt vmcnt(0)" ::: "memory");
    }
    // ---- PV from registers ----
#pragma unroll
    for (int kt = 0; kt < 2; kt++) {
      shortx8 pf0 = *(const shortx8*)(Pw + kt * 1024 + lane * 16);
      shortx8 pf1 = *(const shortx8*)(Pw + 2048 + kt * 1024 + lane * 16);
#pragma unroll
      for (int nt = 0; nt < 8; nt++) {
        O[0][nt] = __builtin_amdgcn_mfma_f32_16x16x32_bf16(pf0, vf[nt][kt], O[0][nt], 0, 0, 0);
        O[1][nt] = __builtin_amdgcn_mfma_f32_16x16x32_bf16(pf1, vf[nt][kt], O[1][nt], 0, 0, 0);
      }
    }
  }
  // epilogue: store partial O and (m,l)
#pragma unroll
  for (int ig = 0; ig < 2; ig++) {
    float* Ob = Opart + ((size_t)(sp * 4 + b) * HW + i0 + w * 32 + ig * 16) * 128;
#pragma unroll
    for (int nt = 0; nt < 8; nt++)
#pragma unroll
      for (int rr = 0; rr < 4; rr++)
        Ob[(size_t)(quad * 4 + rr) * 128 + nt * 16 + l16] = O[ig][nt][rr];
  }
  if (quad == 0) {
    float2* mlp = (float2*)ml;
#pragma unroll
    for (int ig = 0; ig < 2; ig++)
      mlp[(size_t)(sp * 4 + b) * HW + i0 + w * 32 + ig * 16 + l16]
          = make_float2(m_i[ig], l_i[ig]);
  }
}

// ---------------- K4: merge split-j partials -> res ------------------------------------
__global__ __launch_bounds__(256) void k_merge(const float* __restrict__ Opart,
    const float* __restrict__ ml, float* __restrict__ res) {
  size_t e = (size_t)blockIdx.x * 256 + threadIdx.x;  // float4 index
  int cq = (int)(e & 31);
  int i = (int)((e >> 5) & 4095);
  int b = (int)(e >> 17);
  const float2* mlp = (const float2*)ml;
  float m[SPLIT], l[SPLIT];
  float M = -1e30f;
#pragma unroll
  for (int s = 0; s < SPLIT; s++) {
    float2 st = mlp[(size_t)(s * 4 + b) * HW + i];
    m[s] = st.x; l[s] = st.y;
    M = fmaxf(M, m[s]);
  }
  float denom = 0.f;
  float wgt[SPLIT];
#pragma unroll
  for (int s = 0; s < SPLIT; s++) {
    float ws_ = EXP2F((m[s] - M) * L2E);
    wgt[s] = ws_;
    denom += l[s] * ws_;
  }
  float inv = 1.f / denom;
  floatx4 acc = {0.f, 0.f, 0.f, 0.f};
#pragma unroll
  for (int s = 0; s < SPLIT; s++) {
    floatx4 v = *(const floatx4*)(Opart + ((size_t)(s * 4 + b) * HW + i) * 128 + cq * 4);
    acc += v * (wgt[s] * inv);
  }
  *(floatx4*)(res + e * 4) = acc;
}

// ---------------- K5: conv4 (fp32) + BN(eval) + residual ------------------------------
__global__ __launch_bounds__(256) void k_out(const float* __restrict__ res,
    const float* __restrict__ w4, const float* __restrict__ gamma,
    const float* __restrict__ beta, const float* __restrict__ rmean,
    const float* __restrict__ rvar, const float* __restrict__ x,
    float* __restrict__ out) {
  __shared__ float wt[16 * 128];
  int bid = blockIdx.x;
  int cot = bid & 15;
  int st = (bid >> 4) & 15;
  int b = bid >> 8;
  int t = threadIdx.x;
  int co0 = cot * 16;
#pragma unroll
  for (int k = 0; k < 8; k++) wt[k * 256 + t] = w4[(size_t)co0 * 128 + k * 256 + t];
  __syncthreads();
  int px = st * 256 + t;
  const float* rb = res + (size_t)b * 524288 + px;
  float acc[16];
#pragma unroll
  for (int r = 0; r < 16; r++) acc[r] = 0.f;
  for (int ci = 0; ci < 128; ci += 4) {
    float xv[4];
#pragma unroll
    for (int kk = 0; kk < 4; kk++) xv[kk] = rb[(size_t)(ci + kk) * HW];
#pragma unroll
    for (int r = 0; r < 16; r++) {
      floatx4 wv = *(const floatx4*)&wt[r * 128 + ci];
#pragma unroll
      for (int kk = 0; kk < 4; kk++) acc[r] += wv[kk] * xv[kk];
    }
  }
  const float* xb = x + ((size_t)b * 256 + co0) * HW + px;
  float* ob = out + ((size_t)b * 256 + co0) * HW + px;
#pragma unroll
  for (int r = 0; r < 16; r++) {
    int co = co0 + r;
    float g = gamma[co] * rsqrtf(rvar[co] + 1e-5f);
    float bb = beta[co] - rmean[co] * g;
    ob[(size_t)r * HW] = acc[r] * g + bb + xb[(size_t)r * HW];
  }
}

extern "C" void kernel_launch(void* const* d_in, const int* in_sizes, int n_in,
                              void* d_out, int out_size, void* d_ws, size_t ws_size,
                              hipStream_t stream) {
  const float* x     = (const float*)d_in[0];
  const float* w1    = (const float*)d_in[1];
  const float* w2    = (const float*)d_in[2];
  const float* w3    = (const float*)d_in[3];
  const float* w4    = (const float*)d_in[4];
  const float* gamma = (const float*)d_in[5];
  const float* beta  = (const float*)d_in[6];
  const float* rmean = (const float*)d_in[7];
  const float* rvar  = (const float*)d_in[8];
  float* out = (float*)d_out;
  char* ws = (char*)d_ws;

  // Opart region (64 MB, SPLIT=8) overlaps n3 / Xth (dead before k_flash runs)
  size_t off = (size_t)SPLIT * 4 * HW * 128 * 4;             // 64 MB
  float* Opart = (float*)ws;
  unsigned short* n3  = (unsigned short*)ws;                  // 4.2 MB @ 0
  unsigned short* Xth = (unsigned short*)(ws + ((size_t)8 << 20));   // 8.4 MB @ 8M
  unsigned short* Q   = (unsigned short*)(ws + off); off += (size_t)4 * HW * 128 * 2;
  unsigned short* Kt  = (unsigned short*)(ws + off); off += (size_t)4 * HW * 128 * 2;
  unsigned short* VtF = (unsigned short*)(ws + off); off += (size_t)4 * HW * 128 * 2;
  float* ml  = (float*)(ws + off); off += (size_t)SPLIT * 4 * HW * 2 * 4;
  float* res = (float*)(ws + off); off += (size_t)4 * HW * 128 * 4;
  unsigned short* Wh = (unsigned short*)(ws + off); off += (size_t)384 * 256 * 2;
  if (ws_size < off) return;

  k_split   <<<1036, 256, 0, stream>>>(x, w1, w2, w3, Xth, Wh);
  k_projM   <<<768,  256, 0, stream>>>(Xth, Wh, Q, Kt, n3);
  k_layoutVF<<<256,  256, 0, stream>>>(n3, VtF);
  k_flash   <<<1024, 256, 0, stream>>>(Q, Kt, VtF, Opart, ml);
  k_merge   <<<2048, 256, 0, stream>>>(Opart, ml, res);
  k_out     <<<1024, 256, 0, stream>>>(res, w4, gamma, beta, rmean, rvar, x, out);
}

// Round 11
// 193.283 us; speedup vs baseline: 1.7248x; 1.7248x over previous
//
#include <hip/hip_runtime.h>
#include <cstdint>

#define BN 4
#define CIN 256
#define HALFC 128
#define HW 4096
#define SPLIT 6

typedef float  floatx4 __attribute__((ext_vector_type(4)));
typedef short  shortx8 __attribute__((ext_vector_type(8)));

#if __has_builtin(__builtin_amdgcn_exp2f)
#define EXP2F(x) __builtin_amdgcn_exp2f(x)
#else
#define EXP2F(x) exp2f(x)
#endif
#define L2E 1.44269504088896f

__device__ __forceinline__ unsigned short f2bf(float f) {
  unsigned u = __float_as_uint(f);
  u += 0x7FFFu + ((u >> 16) & 1u);   // round-to-nearest-even
  return (unsigned short)(u >> 16);
}

__device__ __forceinline__ void async16(const void* g, void* l) {
  __builtin_amdgcn_global_load_lds((const __attribute__((address_space(1))) void*)g,
                                   (__attribute__((address_space(3))) void*)l, 16, 0, 0);
}

// ---------------- K0: cast/transpose x -> Xt [b][px][ci] bf16; W -> Wh bf16 -----------
__global__ __launch_bounds__(256) void k_split(const float* __restrict__ x,
    const float* __restrict__ w1, const float* __restrict__ w2,
    const float* __restrict__ w3, unsigned short* __restrict__ Xth,
    unsigned short* __restrict__ Wh) {
  __shared__ float smf[64 * 65];
  int bid = blockIdx.x;
  int t = threadIdx.x;
  if (bid < 1024) {
    int b = bid >> 8, rem = bid & 255;
    int cit = rem >> 6, pxt = rem & 63;     // ci tile (4), px tile (64)
    const float* src = x + (size_t)b * 1048576 + (size_t)(cit * 64) * HW + pxt * 64;
#pragma unroll
    for (int k = 0; k < 16; k++) {
      int idx = k * 256 + t;
      int r = idx >> 6, c = idx & 63;
      smf[r * 65 + c] = src[(size_t)r * HW + c];
    }
    __syncthreads();
    int prow = t >> 2, seg = t & 3;
    union { unsigned short us[16]; uint4 v[2]; } oh;
#pragma unroll
    for (int u = 0; u < 16; u++)
      oh.us[u] = f2bf(smf[(seg * 16 + u) * 65 + prow]);
    size_t dst = (size_t)b * 1048576 + (size_t)(pxt * 64 + prow) * 256 + cit * 64 + seg * 16;
    *(uint4*)(Xth + dst) = oh.v[0];
    *(uint4*)(Xth + dst + 8) = oh.v[1];
  } else {
    int bw = bid - 1024;                    // 0..11, each block 8192 elems
    int f0 = bw * 8192 + t * 32;
    const float* wsrc;
    int fo;
    if (f0 < 32768)      { wsrc = w1; fo = f0; }
    else if (f0 < 65536) { wsrc = w2; fo = f0 - 32768; }
    else                 { wsrc = w3; fo = f0 - 65536; }
    union { unsigned short us[32]; uint4 v[4]; } oh;
#pragma unroll
    for (int u = 0; u < 32; u++) oh.us[u] = f2bf(wsrc[fo + u]);
#pragma unroll
    for (int k = 0; k < 4; k++) *((uint4*)(Wh + f0) + k) = oh.v[k];
  }
}

// ---------------- K1: MFMA projection (bf16, fp32 acc), dbuf vmcnt pipeline ------------
__global__ __launch_bounds__(256) void k_projM(const unsigned short* __restrict__ Xth,
    const unsigned short* __restrict__ Wh, unsigned short* __restrict__ Q,
    unsigned short* __restrict__ Kt, unsigned short* __restrict__ n3) {
  __shared__ unsigned short XhS[2 * 8192];  // 2 x 16 KB
  __shared__ unsigned short ES[9216];       // epilogue stage (18 KB)
  int bid = blockIdx.x;
  int pxt = bid & 31;
  int ct = bid >> 5;                        // b*6 + cot
  int b = ct / 6, cot = ct % 6;
  int px0 = pxt * 128, co0 = cot * 64;
  int t = threadIdx.x;
  int w = t >> 6, lane = t & 63, l16 = lane & 15, quad = lane >> 4;

  int myco = co0 + w * 16 + l16;
  shortx8 whf[8];
#pragma unroll
  for (int s = 0; s < 8; s++)
    whf[s] = *(const shortx8*)(Wh + (size_t)myco * 256 + s * 32 + quad * 8);
  __asm__ __volatile__("s_waitcnt vmcnt(0)" ::: "memory");  // drain whf: vmcnt exactness

  floatx4 acc[8];
  floatx4 zf = {0.f, 0.f, 0.f, 0.f};
#pragma unroll
  for (int mt = 0; mt < 8; mt++) acc[mt] = zf;
  const unsigned short* XhB = Xth + (size_t)b * 1048576;

#define PROJ_SRC(r, c4) (XhB + (size_t)(px0 + (((c4) * 4 + w) >> 1) * 16 + l16) * 256 \
                         + (r) * 64 + (((c4) * 4 + w) & 1) * 32 + quad * 8)
#pragma unroll
  for (int c4 = 0; c4 < 4; c4++)
    async16(PROJ_SRC(0, c4), (char*)XhS + c4 * 4096 + w * 1024);

#pragma unroll
  for (int r = 0; r < 4; r++) {
    int cur = r & 1, nxt = cur ^ 1;
    __asm__ __volatile__("s_barrier" ::: "memory");          // compute(r-1) done
    if (r + 1 < 4) {
#pragma unroll
      for (int c4 = 0; c4 < 4; c4++)
        async16(PROJ_SRC(r + 1, c4), (char*)XhS + nxt * 16384 + c4 * 4096 + w * 1024);
      __asm__ __volatile__("s_waitcnt vmcnt(4)" ::: "memory");
    } else {
      __asm__ __volatile__("s_waitcnt vmcnt(0)" ::: "memory");
    }
    __asm__ __volatile__("s_barrier" ::: "memory");          // round-r data landed
    const char* xb = (const char*)XhS + cur * 16384;
#pragma unroll
    for (int sk = 0; sk < 2; sk++)
#pragma unroll
      for (int mt = 0; mt < 8; mt++) {
        shortx8 ah = *(const shortx8*)(xb + (mt * 2 + sk) * 1024 + lane * 16);
        acc[mt] = __builtin_amdgcn_mfma_f32_16x16x32_bf16(ah, whf[r * 2 + sk], acc[mt], 0, 0, 0);
      }
  }
#undef PROJ_SRC
  __syncthreads();
  // D layout: element [px = mt*16 + quad*4 + rr][co_l = w*16 + l16]
  if (cot < 2 || cot >= 4) {             // Q / n3: stage [co][px]
    int co_l = w * 16 + l16;
#pragma unroll
    for (int mt = 0; mt < 8; mt++) {
      int px = mt * 16 + quad * 4;
      unsigned lo = (unsigned)f2bf(acc[mt][0]) | ((unsigned)f2bf(acc[mt][1]) << 16);
      unsigned hi = (unsigned)f2bf(acc[mt][2]) | ((unsigned)f2bf(acc[mt][3]) << 16);
      *(uint2*)(ES + co_l * 136 + px) = make_uint2(lo, hi);
    }
    __syncthreads();
    int cr = t >> 2, seg = t & 3;
    unsigned short* dstb = (cot < 2)
        ? Q  + (size_t)b * 524288 + (size_t)(co0 + cr) * HW
        : n3 + (size_t)b * 524288 + (size_t)(co0 - 256 + cr) * HW;
#pragma unroll
    for (int k2 = 0; k2 < 4; k2++) {
      uint4 v = *(const uint4*)(ES + cr * 136 + seg * 32 + k2 * 8);
      *(uint4*)(dstb + px0 + seg * 32 + k2 * 8) = v;
    }
  } else {                               // Kt: stage [px][co]
#pragma unroll
    for (int mt = 0; mt < 8; mt++)
#pragma unroll
      for (int rr = 0; rr < 4; rr++) {
        int px = mt * 16 + quad * 4 + rr;
        ES[px * 72 + w * 16 + l16] = f2bf(acc[mt][rr]);
      }
    __syncthreads();
    int ch0 = co0 - 128;
#pragma unroll
    for (int it = 0; it < 4; it++) {
      int cid = it * 256 + t;
      int px = cid >> 3, c8 = cid & 7;
      uint4 v = *(const uint4*)(ES + px * 72 + c8 * 8);
      *(uint4*)(Kt + (size_t)b * 524288 + (size_t)(px0 + px) * 128 + ch0 + c8 * 8) = v;
    }
  }
}

// ---------------- K2: VtF: V in wave-fragment order for direct coalesced PV loads ------
__global__ __launch_bounds__(256) void k_layoutVF(const unsigned short* __restrict__ n3,
    unsigned short* __restrict__ VtF) {
  __shared__ unsigned short sm[8192];
  int bid = blockIdx.x;                  // 256 = b(4) x jt(64)
  int b = bid >> 6, jt = bid & 63;
  int t = threadIdx.x;
  const unsigned short* src = n3 + (size_t)b * 524288 + (size_t)(jt * 2) * 4096;
#pragma unroll
  for (int k = 0; k < 32; k++) sm[k * 256 + t] = src[k * 256 + t];
  __syncthreads();
  unsigned short* dst = VtF + (size_t)b * 524288 + (size_t)jt * 8192;
#pragma unroll
  for (int k = 0; k < 4; k++) {
    int s = k * 256 + t;
    int nt = s >> 7, kt = (s >> 6) & 1, quad = (s >> 4) & 3, l16 = s & 15;
    union { unsigned short us[8]; uint4 v; } o;
#pragma unroll
    for (int e = 0; e < 8; e++)
      o.us[e] = sm[kt * 4096 + (quad * 8 + e) * 128 + nt * 16 + l16];
    *(uint4*)(dst + s * 8) = o.v;
  }
}

// ---------------- K3: fused flash attention (SPLIT=6, 3 blocks/CU, register-diet PV) ---
// PV loads V fragments in two kt-halves of 32 regs each (never overlapping S's regs):
// peak unified regs ~155 < 168 budget at 3 waves/SIMD. grid 768 = exactly 3/CU.
__global__ __launch_bounds__(256, 3) void k_flash(const unsigned short* __restrict__ Q,
    const unsigned short* __restrict__ Kt, const unsigned short* __restrict__ VtF,
    float* __restrict__ Opart, float* __restrict__ ml) {
  __shared__ unsigned short KtS[2 * 8192];   // 2 x 16 KB
  __shared__ unsigned short PS[4 * 32 * 64]; // 16 KB (4 KB per wave)
  int bid = blockIdx.x;
  int itile = bid & 31;
  int spb = bid >> 5;                        // 0..23
  int sp = spb % 6, b = spb / 6;
  int tbase  = (sp < 4) ? sp * 11 : 44 + (sp - 4) * 10;   // first 64-j tile
  int jiters = (sp < 4) ? 11 : 10;
  int t = threadIdx.x;
  int w = t >> 6, lane = t & 63, l16 = lane & 15, quad = lane >> 4;
  int i0 = itile * 128;

  shortx8 qf[2][4];
#pragma unroll
  for (int ig = 0; ig < 2; ig++) {
    const unsigned short* qp = Q + ((size_t)b * HW + i0 + w * 32 + ig * 16 + l16) * 128 + quad * 8;
#pragma unroll
    for (int ks = 0; ks < 4; ks++) qf[ig][ks] = *(const shortx8*)(qp + ks * 32);
  }
  __asm__ __volatile__("s_waitcnt vmcnt(0)" ::: "memory");  // drain Q loads

  floatx4 O[2][8];
  floatx4 zf = {0.f, 0.f, 0.f, 0.f};
#pragma unroll
  for (int ig = 0; ig < 2; ig++)
#pragma unroll
    for (int nt = 0; nt < 8; nt++) O[ig][nt] = zf;
  float m_i[2] = {-1e30f, -1e30f}, l_i[2] = {0.f, 0.f};

  int ccK = w * 4 + (lane >> 4);
  const unsigned short* kbase = Kt + (size_t)b * HW * 128
                              + (size_t)(tbase * 64 + l16) * 128 + ccK * 8;
  const unsigned short* vB = VtF + (size_t)b * 524288 + (size_t)tbase * 8192 + lane * 8;
  char* Pw = (char*)PS + w * 4096;

  // prologue: stage Kt tile 0 into buffer 0
#pragma unroll
  for (int c4 = 0; c4 < 4; c4++)
    async16(kbase + c4 * 2048, (char*)KtS + c4 * 4096 + w * 1024);

  for (int it = 0; it < jiters; it++) {
    int cur = it & 1, nxt = cur ^ 1;
    __asm__ __volatile__("s_barrier" ::: "memory");   // compute(it-1) done
    if (it + 1 < jiters) {
      const unsigned short* kp = kbase + (size_t)(it + 1) * 8192;
#pragma unroll
      for (int c4 = 0; c4 < 4; c4++)
        async16(kp + c4 * 2048, (char*)KtS + nxt * 16384 + c4 * 4096 + w * 1024);
      // outstanding: prev prefetch(4, oldest) + new(4); drain prev only
      __asm__ __volatile__("s_waitcnt vmcnt(4)" ::: "memory");
    } else {
      __asm__ __volatile__("s_waitcnt vmcnt(0)" ::: "memory");
    }
    __asm__ __volatile__("s_barrier" ::: "memory");   // tile-it Kt landed

    const char* kc = (const char*)KtS + cur * 16384;

    // ---- QK ----
    floatx4 S[2][4];
#pragma unroll
    for (int ig = 0; ig < 2; ig++)
#pragma unroll
      for (int mt = 0; mt < 4; mt++) S[ig][mt] = zf;
#pragma unroll
    for (int mt = 0; mt < 4; mt++) {
#pragma unroll
      for (int ks = 0; ks < 4; ks++) {
        shortx8 af = *(const shortx8*)(kc + mt * 4096 + ks * 1024 + lane * 16);
        S[0][mt] = __builtin_amdgcn_mfma_f32_16x16x32_bf16(af, qf[0][ks], S[0][mt], 0, 0, 0);
        S[1][mt] = __builtin_amdgcn_mfma_f32_16x16x32_bf16(af, qf[1][ks], S[1][mt], 0, 0, 0);
      }
    }
    // ---- online softmax per i-group; P overwrites S ----
    float alpha[2];
#pragma unroll
    for (int ig = 0; ig < 2; ig++) {
      float tmax = S[ig][0][0];
#pragma unroll
      for (int mt = 0; mt < 4; mt++)
#pragma unroll
        for (int rr = 0; rr < 4; rr++) tmax = fmaxf(tmax, S[ig][mt][rr]);
      tmax = fmaxf(tmax, __shfl_xor(tmax, 16));
      tmax = fmaxf(tmax, __shfl_xor(tmax, 32));
      float mnew = fmaxf(m_i[ig], tmax);
      alpha[ig] = EXP2F((m_i[ig] - mnew) * L2E);
      float tsum = 0.f;
#pragma unroll
      for (int mt = 0; mt < 4; mt++)
#pragma unroll
        for (int rr = 0; rr < 4; rr++) {
          float p = EXP2F((S[ig][mt][rr] - mnew) * L2E);
          S[ig][mt][rr] = p;
          tsum += p;
        }
      tsum += __shfl_xor(tsum, 16);
      tsum += __shfl_xor(tsum, 32);
      l_i[ig] = l_i[ig] * alpha[ig] + tsum;
      m_i[ig] = mnew;
    }
    if (__ballot(alpha[0] < 1.f || alpha[1] < 1.f)) {
#pragma unroll
      for (int ig = 0; ig < 2; ig++) {
        float ar[4];
#pragma unroll
        for (int rr = 0; rr < 4; rr++) ar[rr] = __shfl(alpha[ig], quad * 4 + rr);
#pragma unroll
        for (int nt = 0; nt < 8; nt++)
#pragma unroll
          for (int rr = 0; rr < 4; rr++) O[ig][nt][rr] *= ar[rr];
      }
    }
    // ---- P -> wave-private LDS; truncating bf16 pack via v_perm ----
#pragma unroll
    for (int ig = 0; ig < 2; ig++)
#pragma unroll
      for (int mt = 0; mt < 4; mt++) {
        unsigned lo = __builtin_amdgcn_perm(__float_as_uint(S[ig][mt][1]),
                                            __float_as_uint(S[ig][mt][0]), 0x07060302u);
        unsigned hi = __builtin_amdgcn_perm(__float_as_uint(S[ig][mt][3]),
                                            __float_as_uint(S[ig][mt][2]), 0x07060302u);
        *(uint2*)(Pw + ig * 2048 + (mt * 2 + (quad >> 1)) * 256 + l16 * 16 + (quad & 1) * 8)
            = make_uint2(lo, hi);
      }
    // ---- PV in two kt-halves; vf regs (32) never overlap S's ----
    const unsigned short* vt = vB + (size_t)it * 8192;
    shortx8 vf0[8];
#pragma unroll
    for (int nt = 0; nt < 8; nt++)
      vf0[nt] = *(const shortx8*)(vt + nt * 1024);          // kt=0 fragments
    __asm__ __volatile__("s_waitcnt lgkmcnt(0)" ::: "memory");  // PS write->read
    __asm__ __volatile__("s_waitcnt vmcnt(0)" ::: "memory");    // vf0 (+prefetch, landed)
    {
      shortx8 pf0 = *(const shortx8*)(Pw + lane * 16);
      shortx8 pf1 = *(const shortx8*)(Pw + 2048 + lane * 16);
#pragma unroll
      for (int nt = 0; nt < 8; nt++) {
        O[0][nt] = __builtin_amdgcn_mfma_f32_16x16x32_bf16(pf0, vf0[nt], O[0][nt], 0, 0, 0);
        O[1][nt] = __builtin_amdgcn_mfma_f32_16x16x32_bf16(pf1, vf0[nt], O[1][nt], 0, 0, 0);
      }
    }
    shortx8 vf1[8];
#pragma unroll
    for (int nt = 0; nt < 8; nt++)
      vf1[nt] = *(const shortx8*)(vt + nt * 1024 + 512);    // kt=1 fragments
    __asm__ __volatile__("s_waitcnt vmcnt(0)" ::: "memory");
    {
      shortx8 pf0 = *(const shortx8*)(Pw + 1024 + lane * 16);
      shortx8 pf1 = *(const shortx8*)(Pw + 3072 + lane * 16);
#pragma unroll
      for (int nt = 0; nt < 8; nt++) {
        O[0][nt] = __builtin_amdgcn_mfma_f32_16x16x32_bf16(pf0, vf1[nt], O[0][nt], 0, 0, 0);
        O[1][nt] = __builtin_amdgcn_mfma_f32_16x16x32_bf16(pf1, vf1[nt], O[1][nt], 0, 0, 0);
      }
    }
  }
  // epilogue: store partial O and (m,l)
#pragma unroll
  for (int ig = 0; ig < 2; ig++) {
    float* Ob = Opart + ((size_t)(sp * 4 + b) * HW + i0 + w * 32 + ig * 16) * 128;
#pragma unroll
    for (int nt = 0; nt < 8; nt++)
#pragma unroll
      for (int rr = 0; rr < 4; rr++)
        Ob[(size_t)(quad * 4 + rr) * 128 + nt * 16 + l16] = O[ig][nt][rr];
  }
  if (quad == 0) {
    float2* mlp = (float2*)ml;
#pragma unroll
    for (int ig = 0; ig < 2; ig++)
      mlp[(size_t)(sp * 4 + b) * HW + i0 + w * 32 + ig * 16 + l16]
          = make_float2(m_i[ig], l_i[ig]);
  }
}

// ---------------- K4: merge split-j partials -> res ------------------------------------
__global__ __launch_bounds__(256) void k_merge(const float* __restrict__ Opart,
    const float* __restrict__ ml, float* __restrict__ res) {
  size_t e = (size_t)blockIdx.x * 256 + threadIdx.x;  // float4 index
  int cq = (int)(e & 31);
  int i = (int)((e >> 5) & 4095);
  int b = (int)(e >> 17);
  const float2* mlp = (const float2*)ml;
  float m[SPLIT], l[SPLIT];
  float M = -1e30f;
#pragma unroll
  for (int s = 0; s < SPLIT; s++) {
    float2 st = mlp[(size_t)(s * 4 + b) * HW + i];
    m[s] = st.x; l[s] = st.y;
    M = fmaxf(M, m[s]);
  }
  float denom = 0.f;
  float wgt[SPLIT];
#pragma unroll
  for (int s = 0; s < SPLIT; s++) {
    float ws_ = EXP2F((m[s] - M) * L2E);
    wgt[s] = ws_;
    denom += l[s] * ws_;
  }
  float inv = 1.f / denom;
  floatx4 acc = {0.f, 0.f, 0.f, 0.f};
#pragma unroll
  for (int s = 0; s < SPLIT; s++) {
    floatx4 v = *(const floatx4*)(Opart + ((size_t)(s * 4 + b) * HW + i) * 128 + cq * 4);
    acc += v * (wgt[s] * inv);
  }
  *(floatx4*)(res + e * 4) = acc;
}

// ---------------- K5: conv4 (fp32) + BN(eval) + residual ------------------------------
__global__ __launch_bounds__(256) void k_out(const float* __restrict__ res,
    const float* __restrict__ w4, const float* __restrict__ gamma,
    const float* __restrict__ beta, const float* __restrict__ rmean,
    const float* __restrict__ rvar, const float* __restrict__ x,
    float* __restrict__ out) {
  __shared__ float wt[16 * 128];
  int bid = blockIdx.x;
  int cot = bid & 15;
  int st = (bid >> 4) & 15;
  int b = bid >> 8;
  int t = threadIdx.x;
  int co0 = cot * 16;
#pragma unroll
  for (int k = 0; k < 8; k++) wt[k * 256 + t] = w4[(size_t)co0 * 128 + k * 256 + t];
  __syncthreads();
  int px = st * 256 + t;
  const float* rb = res + (size_t)b * 524288 + px;
  float acc[16];
#pragma unroll
  for (int r = 0; r < 16; r++) acc[r] = 0.f;
  for (int ci = 0; ci < 128; ci += 4) {
    float xv[4];
#pragma unroll
    for (int kk = 0; kk < 4; kk++) xv[kk] = rb[(size_t)(ci + kk) * HW];
#pragma unroll
    for (int r = 0; r < 16; r++) {
      floatx4 wv = *(const floatx4*)&wt[r * 128 + ci];
#pragma unroll
      for (int kk = 0; kk < 4; kk++) acc[r] += wv[kk] * xv[kk];
    }
  }
  const float* xb = x + ((size_t)b * 256 + co0) * HW + px;
  float* ob = out + ((size_t)b * 256 + co0) * HW + px;
#pragma unroll
  for (int r = 0; r < 16; r++) {
    int co = co0 + r;
    float g = gamma[co] * rsqrtf(rvar[co] + 1e-5f);
    float bb = beta[co] - rmean[co] * g;
    ob[(size_t)r * HW] = acc[r] * g + bb + xb[(size_t)r * HW];
  }
}

extern "C" void kernel_launch(void* const* d_in, const int* in_sizes, int n_in,
                              void* d_out, int out_size, void* d_ws, size_t ws_size,
                              hipStream_t stream) {
  const float* x     = (const float*)d_in[0];
  const float* w1    = (const float*)d_in[1];
  const float* w2    = (const float*)d_in[2];
  const float* w3    = (const float*)d_in[3];
  const float* w4    = (const float*)d_in[4];
  const float* gamma = (const float*)d_in[5];
  const float* beta  = (const float*)d_in[6];
  const float* rmean = (const float*)d_in[7];
  const float* rvar  = (const float*)d_in[8];
  float* out = (float*)d_out;
  char* ws = (char*)d_ws;

  // Opart region (48 MB, SPLIT=6) overlaps n3 / Xth (dead before k_flash runs)
  size_t off = (size_t)SPLIT * 4 * HW * 128 * 4;             // 48 MB
  float* Opart = (float*)ws;
  unsigned short* n3  = (unsigned short*)ws;                  // 4.2 MB @ 0
  unsigned short* Xth = (unsigned short*)(ws + ((size_t)8 << 20));   // 8.4 MB @ 8M
  unsigned short* Q   = (unsigned short*)(ws + off); off += (size_t)4 * HW * 128 * 2;
  unsigned short* Kt  = (unsigned short*)(ws + off); off += (size_t)4 * HW * 128 * 2;
  unsigned short* VtF = (unsigned short*)(ws + off); off += (size_t)4 * HW * 128 * 2;
  float* ml  = (float*)(ws + off); off += (size_t)SPLIT * 4 * HW * 2 * 4;
  float* res = (float*)(ws + off); off += (size_t)4 * HW * 128 * 4;
  unsigned short* Wh = (unsigned short*)(ws + off); off += (size_t)384 * 256 * 2;
  if (ws_size < off) return;

  k_split   <<<1036, 256, 0, stream>>>(x, w1, w2, w3, Xth, Wh);
  k_projM   <<<768,  256, 0, stream>>>(Xth, Wh, Q, Kt, n3);
  k_layoutVF<<<256,  256, 0, stream>>>(n3, VtF);
  k_flash   <<<768,  256, 0, stream>>>(Q, Kt, VtF, Opart, ml);
  k_merge   <<<2048, 256, 0, stream>>>(Opart, ml, res);
  k_out     <<<1024, 256, 0, stream>>>(res, w4, gamma, beta, rmean, rvar, x, out);
}